// Round 9
// baseline (237.580 us; speedup 1.0000x reference)
//
#include <hip/hip_runtime.h>
#include <math.h>

#define T_TOK 2048
#define HIDDEN 2048
#define NH 16
#define NKV 8
#define DH 128

typedef unsigned short u16;
typedef __attribute__((ext_vector_type(8))) short bf16x8;
typedef __attribute__((ext_vector_type(4))) float f32x4;

__device__ __forceinline__ u16 f2bf(float f) {
  union { float f; unsigned u; } x; x.f = f;
  unsigned r = (x.u + 0x7fffu + ((x.u >> 16) & 1u)) >> 16;
  return (u16)r;
}

__device__ __forceinline__ float bf2f(u16 v) {
  union { unsigned u; float f; } x; x.u = ((unsigned)v) << 16;
  return x.f;
}

__device__ __forceinline__ void gload16(const void* g, void* l) {
  __builtin_amdgcn_global_load_lds((const __attribute__((address_space(1))) void*)g,
                                   (__attribute__((address_space(3))) void*)l,
                                   16, 0, 0);
}

// -------------------------------------------------------------- fused prepass
// b < 4096            : hidden fp32 -> bf16 (Xb)
// 4096 <= b < 6144    : transpose w_qkv [2048][4096] -> WqkvT bf16 [4096][2048]
// 6144 <= b < 7168    : transpose w_o  [2048][2048] -> WoT  bf16 [2048][2048]
__global__ __launch_bounds__(256) void prepass(const float* __restrict__ hidden,
                                               const float* __restrict__ w_qkv,
                                               const float* __restrict__ w_o,
                                               u16* __restrict__ Xb,
                                               u16* __restrict__ WqkvT,
                                               u16* __restrict__ WoT) {
  __shared__ float tile[64][65];
  const int b = blockIdx.x;
  if (b < 4096) {
    int i = b * 256 + threadIdx.x;
    float4 v = ((const float4*)hidden)[i];
    ushort4 o;
    o.x = f2bf(v.x); o.y = f2bf(v.y); o.z = f2bf(v.z); o.w = f2bf(v.w);
    ((ushort4*)Xb)[i] = o;
    return;
  }
  const float* in; u16* out; int R, Cdim, c0, r0;
  if (b < 6144) {
    int bb = b - 4096;
    in = w_qkv; out = WqkvT; R = 2048; Cdim = 4096;
    c0 = (bb & 63) * 64; r0 = (bb >> 6) * 64;
  } else {
    int bb = b - 6144;
    in = w_o; out = WoT; R = 2048; Cdim = 2048;
    c0 = (bb & 31) * 64; r0 = (bb >> 5) * 64;
  }
  const int tx = threadIdx.x & 63, ty = threadIdx.x >> 6;
#pragma unroll
  for (int i = 0; i < 64; i += 4)
    tile[ty + i][tx] = in[(size_t)(r0 + ty + i) * Cdim + c0 + tx];
  __syncthreads();
#pragma unroll
  for (int i = 0; i < 64; i += 4)
    out[(size_t)(c0 + ty + i) * R + r0 + tx] = f2bf(tile[tx][ty + i]);
}

// sum 2 bf16 partial buffers -> fp32 out
__global__ __launch_bounds__(256) void add_parts2(const u16* __restrict__ a,
                                                  const u16* __restrict__ b,
                                                  float* __restrict__ o, int n4) {
  int i = blockIdx.x * blockDim.x + threadIdx.x;
  if (i < n4) {
    ushort4 x = ((const ushort4*)a)[i], y = ((const ushort4*)b)[i];
    float4 z;
    z.x = bf2f(x.x) + bf2f(y.x);
    z.y = bf2f(x.y) + bf2f(y.y);
    z.z = bf2f(x.z) + bf2f(y.z);
    z.w = bf2f(x.w) + bf2f(y.w);
    ((float4*)o)[i] = z;
  }
}

// ------------------------------------- fused RMSNorm+RoPE and V-transpose
// V is written k-PERMUTED within each 64-token tile (sigma-inv) so the attn
// PV B-fragment (pi contraction order) is one contiguous b128 LDS read.
__global__ __launch_bounds__(256) void rope_vt(const u16* __restrict__ qkv,
                                               const int* __restrict__ pos,
                                               const float* __restrict__ qw,
                                               const float* __restrict__ kw,
                                               u16* __restrict__ Qg,
                                               u16* __restrict__ Kg,
                                               u16* __restrict__ Vt) {
  __shared__ float tile[64][65];
  const int b = blockIdx.x;
  if (b < 12288) {
    const int wave = threadIdx.x >> 6, j = threadIdx.x & 63;
    const int idx = b * 4 + wave;
    const int t = idx & 2047, slot = idx >> 11;
    const float QSC = 0.088388347648318447f * 1.4426950408889634f; // scale*log2e
    const size_t base_i = (size_t)t * 4096 + slot * 128;
    float x1 = bf2f(qkv[base_i + j]);
    float x2 = bf2f(qkv[base_i + j + 64]);
    float ss = x1 * x1 + x2 * x2;
#pragma unroll
    for (int m = 1; m < 64; m <<= 1) ss += __shfl_xor(ss, m);
    float r = rsqrtf(ss * (1.0f / 128.0f) + 1e-6f);
    const bool isq = slot < NH;
    const float* w = isq ? qw : kw;
    float xn1 = x1 * r * w[j], xn2 = x2 * r * w[j + 64];
    float fp = (float)pos[t];
    float inv_freq = exp2f(-(float)j * (13.287712379549449f / 64.0f)); // 10000^(-j/64)
    float ang = fp * inv_freq;
    float sn, cs;
    sincosf(ang, &sn, &cs);
    float o1 = xn1 * cs - xn2 * sn;
    float o2 = xn2 * cs + xn1 * sn;
    if (isq) {
      size_t base = ((size_t)slot * T_TOK + t) * DH;
      Qg[base + j] = f2bf(o1 * QSC); Qg[base + 64 + j] = f2bf(o2 * QSC);
    } else {
      size_t base = ((size_t)(slot - NH) * T_TOK + t) * DH;
      Kg[base + j] = f2bf(o1); Kg[base + 64 + j] = f2bf(o2);
    }
    return;
  }
  const int bb = b - 12288;
  const int h = bb & 7, rest = bb >> 3;
  const int t0 = (rest & 31) * 64, d0 = (rest >> 5) * 64;
  const int tx = threadIdx.x & 63, ty = threadIdx.x >> 6;
#pragma unroll
  for (int i = 0; i < 64; i += 4) {
    size_t gi = (size_t)(t0 + ty + i) * 4096 + (NH + NKV) * DH + h * DH + d0 + tx;
    tile[ty + i][tx] = bf2f(qkv[gi]);
  }
  __syncthreads();
  // sigma-inv: output position tx holds original k-index sx within the tile
  const int sx = ((tx >> 5) * 2 + ((tx >> 2) & 1)) * 16 + ((tx >> 3) & 3) * 4 + (tx & 3);
#pragma unroll
  for (int i = 0; i < 64; i += 4)
    Vt[((size_t)h * DH + d0 + ty + i) * T_TOK + t0 + tx] = f2bf(tile[sx][ty + i]);
}

// ------------------------------------------------------------- GEMM 128x256
// (unchanged — verified counted-vmcnt pipeline)
__global__ __launch_bounds__(512, 2) void gemm128x256(const u16* __restrict__ A,
                                                      const u16* __restrict__ Bt,
                                                      void* __restrict__ Cout,
                                                      int M, int N, int K,
                                                      int lda, int ldb, int obf16) {
  __shared__ __attribute__((aligned(128))) char lds[98304];

  const int nx = N >> 8, ny = M >> 7;
  const int flat = blockIdx.x;
  const int per = gridDim.x >> 3;
  const int swz = (flat & 7) * per + (flat >> 3);
  const int by = swz % ny;
  const int rest = swz / ny;
  const int bx = rest % nx;
  const int bz = rest / nx;
  const int m0 = by << 7, n0 = bx << 8;
  A += (size_t)bz * K;
  Bt += (size_t)bz * K;

  const int tid = threadIdx.x;
  const int wave = tid >> 6, lane = tid & 63;
  const int l15 = lane & 15, quad = lane >> 4;
  const int wr = wave >> 2, wc = wave & 3;

  size_t aoff;
  {
    int chunk = tid;
    int line = chunk >> 3;
    int ls8 = (chunk & 7) ^ (line & 7);
    int row = line * 2 + (ls8 >> 2);
    int ks = ls8 & 3;
    aoff = (size_t)(m0 + row) * lda + ks * 8;
  }
  size_t boff[2];
#pragma unroll
  for (int c = 0; c < 2; ++c) {
    int chunk = c * 512 + tid;
    int line = chunk >> 3;
    int ls8 = (chunk & 7) ^ (line & 7);
    int row = line * 2 + (ls8 >> 2);
    int ks = ls8 & 3;
    boff[c] = (size_t)(n0 + row) * ldb + ks * 8;
  }

#define STAGE(tt) do {                                                   \
    char* da = lds + ((tt) & 3) * 8192 + wave * 1024;                    \
    char* db = lds + 32768 + ((tt) & 3) * 16384 + wave * 1024;           \
    const int kk = (tt) * 32;                                            \
    gload16(A + aoff + kk, da);                                          \
    gload16(Bt + boff[0] + kk, db);                                      \
    gload16(Bt + boff[1] + kk, db + 8192);                               \
  } while (0)

  const int fragoff = (l15 >> 1) * 128 +
                      (((((l15 & 1) << 2) | quad) ^ ((l15 >> 1) & 7)) << 4);

  const f32x4 zero = {0.f, 0.f, 0.f, 0.f};
  f32x4 acc[4][4];
#pragma unroll
  for (int i = 0; i < 4; ++i)
#pragma unroll
    for (int j = 0; j < 4; ++j) acc[i][j] = zero;

  const int NT = K >> 5;
  STAGE(0); STAGE(1); STAGE(2);
  asm volatile("s_waitcnt vmcnt(6)" ::: "memory");
  __builtin_amdgcn_s_barrier();

  for (int t = 0; t < NT; ++t) {
    const char* As = lds + (t & 3) * 8192 + wr * 4096 + fragoff;
    const char* Bs = lds + 32768 + (t & 3) * 16384 + wc * 4096 + fragoff;
    bf16x8 af[4], bfr[4];
#pragma unroll
    for (int mt = 0; mt < 4; ++mt) af[mt] = *(const bf16x8*)(As + mt * 1024);
#pragma unroll
    for (int nt = 0; nt < 4; ++nt) bfr[nt] = *(const bf16x8*)(Bs + nt * 1024);

    if (t + 3 < NT) STAGE(t + 3);

    __builtin_amdgcn_s_setprio(1);
#pragma unroll
    for (int mt = 0; mt < 4; ++mt)
#pragma unroll
      for (int nt = 0; nt < 4; ++nt)
        acc[mt][nt] = __builtin_amdgcn_mfma_f32_16x16x32_bf16(af[mt], bfr[nt], acc[mt][nt], 0, 0, 0);
    __builtin_amdgcn_s_setprio(0);

    const int rem = NT - 1 - t;
    if (rem >= 3)      asm volatile("s_waitcnt vmcnt(6)" ::: "memory");
    else if (rem == 2) asm volatile("s_waitcnt vmcnt(3)" ::: "memory");
    else if (rem == 1) asm volatile("s_waitcnt vmcnt(0)" ::: "memory");
    if (rem > 0) __builtin_amdgcn_s_barrier();
  }
#undef STAGE

  if (obf16) {
    u16* C = (u16*)Cout + (size_t)bz * M * N;
#pragma unroll
    for (int mt = 0; mt < 4; ++mt)
#pragma unroll
      for (int nt = 0; nt < 4; ++nt)
#pragma unroll
        for (int r = 0; r < 4; ++r)
          C[(size_t)(m0 + wr * 64 + mt * 16 + quad * 4 + r) * N + n0 + wc * 64 + nt * 16 + l15] =
              f2bf(acc[mt][nt][r]);
  } else {
    float* C = (float*)Cout + (size_t)bz * M * N;
#pragma unroll
    for (int mt = 0; mt < 4; ++mt)
#pragma unroll
      for (int nt = 0; nt < 4; ++nt)
#pragma unroll
        for (int r = 0; r < 4; ++r)
          C[(size_t)(m0 + wr * 64 + mt * 16 + quad * 4 + r) * N + n0 + wc * 64 + nt * 16 + l15] =
              acc[mt][nt][r];
  }
}

// ------------------------------------------------------------- flash attn
// Paired direct-output + 32-row waves + k-parity split.
// Block b = (h, pr): q-tiles {31-pr} and {pr}. 8 waves = 2 k-parities x
// [2 waves HI(32 rows) + 2 waves LO(32 rows)]. Group gp processes k-tiles
// j = 2t+gp; each superstep covers TWO k-tiles -> critical block runs 16
// supersteps instead of 32. Per wave per tile: 16 kf + 16 vf b128 reads feed
// 64 MFMA (2 q-slices share every fragment). Partial O/l combined via LDS at
// the end; normalized bf16 written directly (no merge kernel, no fp32 partials).
// LDS: K/V 2-slot x 2-parity = 128KB + 1KB l-exchange. 256 blocks, 1/CU.
__global__ __launch_bounds__(512, 2) void attn_kernel(const u16* __restrict__ Qg,
                                                      const u16* __restrict__ Kg,
                                                      const u16* __restrict__ Vtg,
                                                      u16* __restrict__ Og) {
  __shared__ u16 Klds[2][2][64 * 128];   // [slot][parity][s][d], group g at g^(s&15)
  __shared__ u16 Vlds[2][2][128 * 64];   // [slot][parity][d][p], group g at g^(d&7)
  __shared__ float Lx[128];              // l exchange: [w4][32]
  const int tid = threadIdx.x;
  const int wave = tid >> 6, lane = tid & 63;
  const int l15 = lane & 15, quad = lane >> 4;
  const int gp = wave >> 2, w4 = wave & 3;
  const int b = blockIdx.x;
  const int h = b & 15, pr = b >> 4;
  const int kvh = h >> 1;
  const int qtHI = 31 - pr, qtLO = pr;
  const int myqt = (w4 < 2) ? qtHI : qtLO;
  const int qbase = myqt * 64 + (w4 & 1) * 32;   // this wave's 32 q-rows
  const int jmax = qtHI + 1;
  const int T = (jmax + 1) >> 1;                 // supersteps (pairs of k-tiles)
  const f32x4 zero = {0.f, 0.f, 0.f, 0.f};

  const u16* Qh = Qg + (size_t)h * T_TOK * DH;
  const u16* Kh = Kg + (size_t)kvh * T_TOK * DH;
  const u16* Vh = Vtg + (size_t)kvh * DH * T_TOK;

#define STAGEPAIR(t2, sl) do {                                          \
    _Pragma("unroll")                                                   \
    for (int c = 0; c < 4; ++c) {                                       \
      int cg = wave * 4 + c;            /* [0,32) */                    \
      int tp = cg >> 4;                 /* tile parity */               \
      int cw = cg & 15;                                                 \
      int sL = cw * 64 + lane;          /* [0,1024) chunk in tile */    \
      int jj = (t2) + tp;                                               \
      { int ss = sL >> 4;                                               \
        int g = (sL & 15) ^ (ss & 15);                                  \
        gload16(Kh + ((size_t)(jj * 64 + ss)) * DH + g * 8,             \
                &Klds[sl][tp][0] + cw * 512); }                         \
      { int d = sL >> 3;                                                \
        int gv = (sL & 7) ^ (d & 7);                                    \
        gload16(Vh + (size_t)d * T_TOK + jj * 64 + gv * 8,              \
                &Vlds[sl][tp][0] + cw * 512); }                         \
    } } while (0)

  bf16x8 qfa[4], qfb[4];
#pragma unroll
  for (int ks = 0; ks < 4; ++ks) {
    qfa[ks] = *(const bf16x8*)(Qh + (size_t)(qbase + l15) * DH + ks * 32 + quad * 8);
    qfb[ks] = *(const bf16x8*)(Qh + (size_t)(qbase + 16 + l15) * DH + ks * 32 + quad * 8);
  }

  f32x4 oa[8], ob[8];
#pragma unroll
  for (int i = 0; i < 8; ++i) { oa[i] = zero; ob[i] = zero; }
  float la = 0.f, lb = 0.f;

  // prologue: stage first pair, drain, make visible
  STAGEPAIR(0, 0);
  asm volatile("s_waitcnt vmcnt(0)" ::: "memory");
  __builtin_amdgcn_s_barrier();

  for (int t = 0; t < T; ++t) {
    const int sl = t & 1;
    const bool more = (t + 1 < T);
    if (more) STAGEPAIR(2 * t + 2, sl ^ 1);   // issue-early into other slot
    const int j = 2 * t + gp;                 // this group's k-tile
    if (j <= myqt) {
      const u16* Kl = &Klds[sl][gp][0];
      const u16* Vl = &Vlds[sl][gp][0];

      // S' = K (Q*scale*log2e)^T for both q-slices; kf read ONCE
      f32x4 sa[4], sb[4];
#pragma unroll
      for (int nt = 0; nt < 4; ++nt) { sa[nt] = zero; sb[nt] = zero; }
      __builtin_amdgcn_s_setprio(1);
#pragma unroll
      for (int nt = 0; nt < 4; ++nt) {
        int sr = nt * 16 + l15;
#pragma unroll
        for (int ks = 0; ks < 4; ++ks) {
          bf16x8 kf = *(const bf16x8*)&Kl[sr * 128 + (((ks * 4 + quad) ^ (sr & 15)) * 8)];
          sa[nt] = __builtin_amdgcn_mfma_f32_16x16x32_bf16(kf, qfa[ks], sa[nt], 0, 0, 0);
          sb[nt] = __builtin_amdgcn_mfma_f32_16x16x32_bf16(kf, qfb[ks], sb[nt], 0, 0, 0);
        }
      }
      __builtin_amdgcn_s_setprio(0);

      if (j == myqt) {                  // diagonal tile: causal mask per slice
        int qA = qbase + l15, qB = qA + 16;
#pragma unroll
        for (int nt = 0; nt < 4; ++nt)
#pragma unroll
          for (int r = 0; r < 4; ++r) {
            int k = j * 64 + nt * 16 + quad * 4 + r;
            if (k > qA) sa[nt][r] = -INFINITY;
            if (k > qB) sb[nt][r] = -INFINITY;
          }
      }

      // P = exp2(S') -> bf16, packed in registers as PV A-frags (pi order)
      union { unsigned d[4]; bf16x8 v; } paA[2], paB[2];
#pragma unroll
      for (int ks = 0; ks < 2; ++ks)
#pragma unroll
        for (int w = 0; w < 4; ++w) {
          int nt = ks * 2 + (w >> 1), rp = (w & 1) * 2;
          unsigned ulo = __float_as_uint(exp2f(sa[nt][rp]));
          unsigned uhi = __float_as_uint(exp2f(sa[nt][rp + 1]));
          la += __uint_as_float(ulo & 0xffff0000u) + __uint_as_float(uhi & 0xffff0000u);
          paA[ks].d[w] = (ulo >> 16) | (uhi & 0xffff0000u);
          unsigned vlo = __float_as_uint(exp2f(sb[nt][rp]));
          unsigned vhi = __float_as_uint(exp2f(sb[nt][rp + 1]));
          lb += __uint_as_float(vlo & 0xffff0000u) + __uint_as_float(vhi & 0xffff0000u);
          paB[ks].d[w] = (vlo >> 16) | (vhi & 0xffff0000u);
        }

      // O += P V for both slices; vf read ONCE (V pre-permuted in global)
      __builtin_amdgcn_s_setprio(1);
#pragma unroll
      for (int ot = 0; ot < 8; ++ot) {
        int d = ot * 16 + l15;
#pragma unroll
        for (int ks = 0; ks < 2; ++ks) {
          bf16x8 vf = *(const bf16x8*)&Vl[d * 64 + (((ks * 4 + quad) ^ (d & 7)) * 8)];
          oa[ot] = __builtin_amdgcn_mfma_f32_16x16x32_bf16(paA[ks].v, vf, oa[ot], 0, 0, 0);
          ob[ot] = __builtin_amdgcn_mfma_f32_16x16x32_bf16(paB[ks].v, vf, ob[ot], 0, 0, 0);
        }
      }
      __builtin_amdgcn_s_setprio(0);
    }

    if (more) {                         // next pair landed; make visible
      asm volatile("s_waitcnt vmcnt(0)" ::: "memory");
      __builtin_amdgcn_s_barrier();
    }
  }

  // reduce l across quads: every lane holds full partial l for q = l15
  la += __shfl_xor(la, 16); la += __shfl_xor(la, 32);
  lb += __shfl_xor(lb, 16); lb += __shfl_xor(lb, 32);

  // combine the two k-parity groups via LDS, then normalize + store bf16
  __syncthreads();                      // all K/V reads done; LDS reusable
  float* Olds = (float*)&Klds[0][0][0]; // 64KB: 4 wave-pairs x 32 x 128 f32
  if (gp == 1) {
    float* Ow = Olds + (size_t)w4 * (32 * 128);
#pragma unroll
    for (int ot = 0; ot < 8; ++ot)
#pragma unroll
      for (int r = 0; r < 4; ++r) {
        Ow[(quad * 4 + r) * 128 + ot * 16 + l15] = oa[ot][r];
        Ow[(16 + quad * 4 + r) * 128 + ot * 16 + l15] = ob[ot][r];
      }
    if (quad == 0) {
      Lx[w4 * 32 + l15] = la;
      Lx[w4 * 32 + 16 + l15] = lb;
    }
  }
  __syncthreads();
  if (gp == 0) {
    const float* Or = Olds + (size_t)w4 * (32 * 128);
    float rlA[4], rlB[4];
#pragma unroll
    for (int r = 0; r < 4; ++r) {
      int i = quad * 4 + r;
      rlA[r] = 1.0f / (__shfl(la, i) + Lx[w4 * 32 + i]);
      rlB[r] = 1.0f / (__shfl(lb, i) + Lx[w4 * 32 + 16 + i]);
    }
#pragma unroll
    for (int ot = 0; ot < 8; ++ot)
#pragma unroll
      for (int r = 0; r < 4; ++r) {
        int rowA = qbase + quad * 4 + r;
        Og[(size_t)rowA * (NH * DH) + h * DH + ot * 16 + l15] =
            f2bf((oa[ot][r] + Or[(quad * 4 + r) * 128 + ot * 16 + l15]) * rlA[r]);
        int rowB = rowA + 16;
        Og[(size_t)rowB * (NH * DH) + h * DH + ot * 16 + l15] =
            f2bf((ob[ot][r] + Or[(16 + quad * 4 + r) * 128 + ot * 16 + l15]) * rlB[r]);
      }
  }
#undef STAGEPAIR
}

// ------------------------------------------------------------------ launch
extern "C" void kernel_launch(void* const* d_in, const int* in_sizes, int n_in,
                              void* d_out, int out_size, void* d_ws, size_t ws_size,
                              hipStream_t stream) {
  (void)in_sizes; (void)n_in; (void)out_size; (void)ws_size;
  const int* positions = (const int*)d_in[0];
  const float* hidden  = (const float*)d_in[1];
  const float* w_qkv   = (const float*)d_in[2];
  const float* w_o     = (const float*)d_in[3];
  const float* q_norm  = (const float*)d_in[4];
  const float* k_norm  = (const float*)d_in[5];
  float* out = (float*)d_out;

  char* ws = (char*)d_ws;                             // peak use 64 MiB
  u16*   Xb    = (u16*)(ws);                          //  8 MiB [dead after GEMM1]
  u16*   WqkvT = (u16*)(ws + ( 8ull << 20));          // 16 MiB [dead after GEMM1]
  u16*   WoT   = (u16*)(ws + (24ull << 20));          //  8 MiB [live till GEMM2]
  u16*   P0    = (u16*)(ws + (32ull << 20));          // 16 MiB: GEMM1 bf16 out (no split)
  // after GEMM1, WqkvT region dead -> Q/K/V live there:
  u16*   Qg    = (u16*)(ws + ( 8ull << 20));          //  8 MiB bf16 [NH][T][D]
  u16*   Kg    = (u16*)(ws + (16ull << 20));          //  4 MiB bf16 [NKV][T][D]
  u16*   Vt    = (u16*)(ws + (20ull << 20));          //  4 MiB bf16 [NKV][D][T] (k-permuted)
  u16*   AttnO = (u16*)(ws + (48ull << 20));          //  8 MiB bf16 [T][NH*D]
  // after rope_vt, P0 region reused:
  u16*   G2P   = (u16*)(ws + (32ull << 20));          // 16 MiB: GEMM2 bf16 partials (2 x 8 MiB)

  prepass<<<dim3(7168), 256, 0, stream>>>(hidden, w_qkv, w_o, Xb, WqkvT, WoT);

  // QKV proj: 128x256 tiles, NO split-K -> 16x16 = 256 blocks (1/CU)
  gemm128x256<<<dim3(256), 512, 0, stream>>>(
      Xb, WqkvT, P0, T_TOK, 4096, HIDDEN, HIDDEN, HIDDEN, 1);

  rope_vt<<<dim3(12288 + 512), 256, 0, stream>>>(P0, positions,
                                                 q_norm, k_norm, Qg, Kg, Vt);

  // paired direct-output attention, k-parity split: 256 blocks = (h, pair)
  attn_kernel<<<dim3(256), 512, 0, stream>>>(Qg, Kg, Vt, AttnO);

  // O-proj: 128x256 tiles, split-K=2 -> 16x8x2 = 256 blocks (1/CU)
  gemm128x256<<<dim3(256), 512, 0, stream>>>(
      AttnO, WoT, G2P, T_TOK, HIDDEN, 1024, NH * DH, NH * DH, 1);
  const int n4 = T_TOK * HIDDEN / 4;
  add_parts2<<<dim3(n4 / 256), 256, 0, stream>>>(
      G2P, G2P + (size_t)T_TOK * HIDDEN, out, n4);
}

// Round 10
// 231.002 us; speedup vs baseline: 1.0285x; 1.0285x over previous
//
#include <hip/hip_runtime.h>
#include <math.h>

#define T_TOK 2048
#define HIDDEN 2048
#define NH 16
#define NKV 8
#define DH 128

typedef unsigned short u16;
typedef __attribute__((ext_vector_type(8))) short bf16x8;
typedef __attribute__((ext_vector_type(4))) float f32x4;

__device__ __forceinline__ u16 f2bf(float f) {
  union { float f; unsigned u; } x; x.f = f;
  unsigned r = (x.u + 0x7fffu + ((x.u >> 16) & 1u)) >> 16;
  return (u16)r;
}

__device__ __forceinline__ float bf2f(u16 v) {
  union { unsigned u; float f; } x; x.u = ((unsigned)v) << 16;
  return x.f;
}

__device__ __forceinline__ void gload16(const void* g, void* l) {
  __builtin_amdgcn_global_load_lds((const __attribute__((address_space(1))) void*)g,
                                   (__attribute__((address_space(3))) void*)l,
                                   16, 0, 0);
}

// -------------------------------------------------------------- fused prepass
// b < 4096            : hidden fp32 -> bf16 (Xb)
// 4096 <= b < 6144    : transpose w_qkv [2048][4096] -> WqkvT bf16 [4096][2048]
// 6144 <= b < 7168    : transpose w_o  [2048][2048] -> WoT  bf16 [2048][2048]
__global__ __launch_bounds__(256) void prepass(const float* __restrict__ hidden,
                                               const float* __restrict__ w_qkv,
                                               const float* __restrict__ w_o,
                                               u16* __restrict__ Xb,
                                               u16* __restrict__ WqkvT,
                                               u16* __restrict__ WoT) {
  __shared__ float tile[64][65];
  const int b = blockIdx.x;
  if (b < 4096) {
    int i = b * 256 + threadIdx.x;
    float4 v = ((const float4*)hidden)[i];
    ushort4 o;
    o.x = f2bf(v.x); o.y = f2bf(v.y); o.z = f2bf(v.z); o.w = f2bf(v.w);
    ((ushort4*)Xb)[i] = o;
    return;
  }
  const float* in; u16* out; int R, Cdim, c0, r0;
  if (b < 6144) {
    int bb = b - 4096;
    in = w_qkv; out = WqkvT; R = 2048; Cdim = 4096;
    c0 = (bb & 63) * 64; r0 = (bb >> 6) * 64;
  } else {
    int bb = b - 6144;
    in = w_o; out = WoT; R = 2048; Cdim = 2048;
    c0 = (bb & 31) * 64; r0 = (bb >> 5) * 64;
  }
  const int tx = threadIdx.x & 63, ty = threadIdx.x >> 6;
#pragma unroll
  for (int i = 0; i < 64; i += 4)
    tile[ty + i][tx] = in[(size_t)(r0 + ty + i) * Cdim + c0 + tx];
  __syncthreads();
#pragma unroll
  for (int i = 0; i < 64; i += 4)
    out[(size_t)(c0 + ty + i) * R + r0 + tx] = f2bf(tile[tx][ty + i]);
}

// sum 2 bf16 partial buffers -> fp32 out
__global__ __launch_bounds__(256) void add_parts2(const u16* __restrict__ a,
                                                  const u16* __restrict__ b,
                                                  float* __restrict__ o, int n4) {
  int i = blockIdx.x * blockDim.x + threadIdx.x;
  if (i < n4) {
    ushort4 x = ((const ushort4*)a)[i], y = ((const ushort4*)b)[i];
    float4 z;
    z.x = bf2f(x.x) + bf2f(y.x);
    z.y = bf2f(x.y) + bf2f(y.y);
    z.z = bf2f(x.z) + bf2f(y.z);
    z.w = bf2f(x.w) + bf2f(y.w);
    ((float4*)o)[i] = z;
  }
}

// ------------------------------------- fused RMSNorm+RoPE and V-transpose
// V is written k-PERMUTED within each 64-token tile (sigma-inv) so the attn
// PV B-fragment (pi contraction order) is one contiguous b128 LDS read.
__global__ __launch_bounds__(256) void rope_vt(const u16* __restrict__ qkv,
                                               const int* __restrict__ pos,
                                               const float* __restrict__ qw,
                                               const float* __restrict__ kw,
                                               u16* __restrict__ Qg,
                                               u16* __restrict__ Kg,
                                               u16* __restrict__ Vt) {
  __shared__ float tile[64][65];
  const int b = blockIdx.x;
  if (b < 12288) {
    const int wave = threadIdx.x >> 6, j = threadIdx.x & 63;
    const int idx = b * 4 + wave;
    const int t = idx & 2047, slot = idx >> 11;
    const float QSC = 0.088388347648318447f * 1.4426950408889634f; // scale*log2e
    const size_t base_i = (size_t)t * 4096 + slot * 128;
    float x1 = bf2f(qkv[base_i + j]);
    float x2 = bf2f(qkv[base_i + j + 64]);
    float ss = x1 * x1 + x2 * x2;
#pragma unroll
    for (int m = 1; m < 64; m <<= 1) ss += __shfl_xor(ss, m);
    float r = rsqrtf(ss * (1.0f / 128.0f) + 1e-6f);
    const bool isq = slot < NH;
    const float* w = isq ? qw : kw;
    float xn1 = x1 * r * w[j], xn2 = x2 * r * w[j + 64];
    float fp = (float)pos[t];
    float inv_freq = exp2f(-(float)j * (13.287712379549449f / 64.0f)); // 10000^(-j/64)
    float ang = fp * inv_freq;
    float sn, cs;
    sincosf(ang, &sn, &cs);
    float o1 = xn1 * cs - xn2 * sn;
    float o2 = xn2 * cs + xn1 * sn;
    if (isq) {
      size_t base = ((size_t)slot * T_TOK + t) * DH;
      Qg[base + j] = f2bf(o1 * QSC); Qg[base + 64 + j] = f2bf(o2 * QSC);
    } else {
      size_t base = ((size_t)(slot - NH) * T_TOK + t) * DH;
      Kg[base + j] = f2bf(o1); Kg[base + 64 + j] = f2bf(o2);
    }
    return;
  }
  const int bb = b - 12288;
  const int h = bb & 7, rest = bb >> 3;
  const int t0 = (rest & 31) * 64, d0 = (rest >> 5) * 64;
  const int tx = threadIdx.x & 63, ty = threadIdx.x >> 6;
#pragma unroll
  for (int i = 0; i < 64; i += 4) {
    size_t gi = (size_t)(t0 + ty + i) * 4096 + (NH + NKV) * DH + h * DH + d0 + tx;
    tile[ty + i][tx] = bf2f(qkv[gi]);
  }
  __syncthreads();
  // sigma-inv: output position tx holds original k-index sx within the tile
  const int sx = ((tx >> 5) * 2 + ((tx >> 2) & 1)) * 16 + ((tx >> 3) & 3) * 4 + (tx & 3);
#pragma unroll
  for (int i = 0; i < 64; i += 4)
    Vt[((size_t)h * DH + d0 + ty + i) * T_TOK + t0 + tx] = f2bf(tile[sx][ty + i]);
}

// ------------------------------------------------------------- GEMM 128x256
// (unchanged — verified counted-vmcnt pipeline)
__global__ __launch_bounds__(512, 2) void gemm128x256(const u16* __restrict__ A,
                                                      const u16* __restrict__ Bt,
                                                      void* __restrict__ Cout,
                                                      int M, int N, int K,
                                                      int lda, int ldb, int obf16) {
  __shared__ __attribute__((aligned(128))) char lds[98304];

  const int nx = N >> 8, ny = M >> 7;
  const int flat = blockIdx.x;
  const int per = gridDim.x >> 3;
  const int swz = (flat & 7) * per + (flat >> 3);
  const int by = swz % ny;
  const int rest = swz / ny;
  const int bx = rest % nx;
  const int bz = rest / nx;
  const int m0 = by << 7, n0 = bx << 8;
  A += (size_t)bz * K;
  Bt += (size_t)bz * K;

  const int tid = threadIdx.x;
  const int wave = tid >> 6, lane = tid & 63;
  const int l15 = lane & 15, quad = lane >> 4;
  const int wr = wave >> 2, wc = wave & 3;

  size_t aoff;
  {
    int chunk = tid;
    int line = chunk >> 3;
    int ls8 = (chunk & 7) ^ (line & 7);
    int row = line * 2 + (ls8 >> 2);
    int ks = ls8 & 3;
    aoff = (size_t)(m0 + row) * lda + ks * 8;
  }
  size_t boff[2];
#pragma unroll
  for (int c = 0; c < 2; ++c) {
    int chunk = c * 512 + tid;
    int line = chunk >> 3;
    int ls8 = (chunk & 7) ^ (line & 7);
    int row = line * 2 + (ls8 >> 2);
    int ks = ls8 & 3;
    boff[c] = (size_t)(n0 + row) * ldb + ks * 8;
  }

#define STAGE(tt) do {                                                   \
    char* da = lds + ((tt) & 3) * 8192 + wave * 1024;                    \
    char* db = lds + 32768 + ((tt) & 3) * 16384 + wave * 1024;           \
    const int kk = (tt) * 32;                                            \
    gload16(A + aoff + kk, da);                                          \
    gload16(Bt + boff[0] + kk, db);                                      \
    gload16(Bt + boff[1] + kk, db + 8192);                               \
  } while (0)

  const int fragoff = (l15 >> 1) * 128 +
                      (((((l15 & 1) << 2) | quad) ^ ((l15 >> 1) & 7)) << 4);

  const f32x4 zero = {0.f, 0.f, 0.f, 0.f};
  f32x4 acc[4][4];
#pragma unroll
  for (int i = 0; i < 4; ++i)
#pragma unroll
    for (int j = 0; j < 4; ++j) acc[i][j] = zero;

  const int NT = K >> 5;
  STAGE(0); STAGE(1); STAGE(2);
  asm volatile("s_waitcnt vmcnt(6)" ::: "memory");
  __builtin_amdgcn_s_barrier();

  for (int t = 0; t < NT; ++t) {
    const char* As = lds + (t & 3) * 8192 + wr * 4096 + fragoff;
    const char* Bs = lds + 32768 + (t & 3) * 16384 + wc * 4096 + fragoff;
    bf16x8 af[4], bfr[4];
#pragma unroll
    for (int mt = 0; mt < 4; ++mt) af[mt] = *(const bf16x8*)(As + mt * 1024);
#pragma unroll
    for (int nt = 0; nt < 4; ++nt) bfr[nt] = *(const bf16x8*)(Bs + nt * 1024);

    if (t + 3 < NT) STAGE(t + 3);

    __builtin_amdgcn_s_setprio(1);
#pragma unroll
    for (int mt = 0; mt < 4; ++mt)
#pragma unroll
      for (int nt = 0; nt < 4; ++nt)
        acc[mt][nt] = __builtin_amdgcn_mfma_f32_16x16x32_bf16(af[mt], bfr[nt], acc[mt][nt], 0, 0, 0);
    __builtin_amdgcn_s_setprio(0);

    const int rem = NT - 1 - t;
    if (rem >= 3)      asm volatile("s_waitcnt vmcnt(6)" ::: "memory");
    else if (rem == 2) asm volatile("s_waitcnt vmcnt(3)" ::: "memory");
    else if (rem == 1) asm volatile("s_waitcnt vmcnt(0)" ::: "memory");
    if (rem > 0) __builtin_amdgcn_s_barrier();
  }
#undef STAGE

  if (obf16) {
    u16* C = (u16*)Cout + (size_t)bz * M * N;
#pragma unroll
    for (int mt = 0; mt < 4; ++mt)
#pragma unroll
      for (int nt = 0; nt < 4; ++nt)
#pragma unroll
        for (int r = 0; r < 4; ++r)
          C[(size_t)(m0 + wr * 64 + mt * 16 + quad * 4 + r) * N + n0 + wc * 64 + nt * 16 + l15] =
              f2bf(acc[mt][nt][r]);
  } else {
    float* C = (float*)Cout + (size_t)bz * M * N;
#pragma unroll
    for (int mt = 0; mt < 4; ++mt)
#pragma unroll
      for (int nt = 0; nt < 4; ++nt)
#pragma unroll
        for (int r = 0; r < 4; ++r)
          C[(size_t)(m0 + wr * 64 + mt * 16 + quad * 4 + r) * N + n0 + wc * 64 + nt * 16 + l15] =
              acc[mt][nt][r];
  }
}

// ------------------------------------------------------------- flash attn
// Balanced cooperative pairing, all SIMDs 2-busy-chains every step.
// Block b=(h,pr): q-tiles HI=31-pr, LO=pr. group0 = waves 0-3, group1 = 4-7
// (SIMD s hosts one wave of each group). 17 uniform steps:
//  phase 1 (t<=pr): ONE staged tile t; g0 computes HI, g1 computes LO.
//  phase 2 (t>pr):  TWO staged tiles pr+1+2u (g0,HI) and pr+2+2u (g1,HI).
// Staging = 32-pr tiles, each staged once. Per-wave body identical to the
// verified R8 kernel (16-row waves, swapped QK^T, in-reg pi-packed P,
// k-permuted V -> conflict-free b128 vf). HI combined across groups via LDS;
// LO written by g1 alone. Direct bf16 output, no merge kernel.
__global__ __launch_bounds__(512, 2) void attn_kernel(const u16* __restrict__ Qg,
                                                      const u16* __restrict__ Kg,
                                                      const u16* __restrict__ Vtg,
                                                      u16* __restrict__ Og) {
  __shared__ u16 Klds[2][2][64 * 128];   // [slot][sub][s][d], group g at g^(s&15)
  __shared__ u16 Vlds[2][2][128 * 64];   // [slot][sub][d][p], group g at g^(d&7)
  __shared__ float Lx[64];               // l exchange for HI: [w4][16]
  const int tid = threadIdx.x;
  const int wave = tid >> 6, lane = tid & 63;
  const int l15 = lane & 15, quad = lane >> 4;
  const int gp = wave >> 2, w4 = wave & 3;
  const int b = blockIdx.x;
  const int h = b & 15, pr = b >> 4;
  const int kvh = h >> 1;
  const int qtHI = 31 - pr, qtLO = pr;
  const f32x4 zero = {0.f, 0.f, 0.f, 0.f};

  const u16* Qh = Qg + (size_t)h * T_TOK * DH;
  const u16* Kh = Kg + (size_t)kvh * T_TOK * DH;
  const u16* Vh = Vtg + (size_t)kvh * DH * T_TOK;
  const int qbH = qtHI * 64 + w4 * 16;   // HI rows (both groups, phase 2)
  const int qbL = qtLO * 64 + w4 * 16;   // LO rows (group 1, phase 1)

#define STAGE1(jj, sl, ss) do {                                         \
    u16* Kd = &Klds[sl][ss][0]; u16* Vd = &Vlds[sl][ss][0];             \
    _Pragma("unroll")                                                   \
    for (int c = 0; c < 2; ++c) {                                       \
      int chunk = wave * 2 + c;                                         \
      int sL = chunk * 64 + lane;                                       \
      { int ssk = sL >> 4;                                              \
        int g = (sL & 15) ^ (ssk & 15);                                 \
        gload16(Kh + ((size_t)((jj) * 64 + ssk)) * DH + g * 8, Kd + chunk * 512); } \
      { int d = sL >> 3;                                                \
        int gv = (sL & 7) ^ (d & 7);                                    \
        gload16(Vh + (size_t)d * T_TOK + (jj) * 64 + gv * 8, Vd + chunk * 512); } \
    } } while (0)

#define STAGESTEP(ts, sl) do {                                          \
    if ((ts) <= pr) { STAGE1((ts), (sl), 0); }                          \
    else {                                                              \
      int uu = (ts) - pr - 1;                                           \
      int jA = pr + 1 + 2 * uu;                                         \
      STAGE1(jA, (sl), 0);                                              \
      if (jA + 1 <= qtHI) STAGE1(jA + 1, (sl), 1);                      \
    } } while (0)

// verified R8 per-tile body: QF/OACC/LACC selected statically per branch
#define TILE_BODY(QF, OACC, LACC, QT, JJ, KL, VL) do {                  \
    f32x4 sacc[4];                                                      \
    _Pragma("unroll")                                                   \
    for (int nt = 0; nt < 4; ++nt) sacc[nt] = zero;                     \
    __builtin_amdgcn_s_setprio(1);                                      \
    _Pragma("unroll")                                                   \
    for (int nt = 0; nt < 4; ++nt) {                                    \
      int sr = nt * 16 + l15;                                           \
      _Pragma("unroll")                                                 \
      for (int ks = 0; ks < 4; ++ks) {                                  \
        bf16x8 kf = *(const bf16x8*)&(KL)[sr * 128 + (((ks * 4 + quad) ^ (sr & 15)) * 8)]; \
        sacc[nt] = __builtin_amdgcn_mfma_f32_16x16x32_bf16(kf, (QF)[ks], sacc[nt], 0, 0, 0); \
      }                                                                 \
    }                                                                   \
    __builtin_amdgcn_s_setprio(0);                                      \
    if ((JJ) == (QT)) {                                                 \
      int q = (QT) * 64 + w4 * 16 + l15;                                \
      _Pragma("unroll")                                                 \
      for (int nt = 0; nt < 4; ++nt)                                    \
        _Pragma("unroll")                                               \
        for (int r = 0; r < 4; ++r) {                                   \
          int k = (JJ) * 64 + nt * 16 + quad * 4 + r;                   \
          if (k > q) sacc[nt][r] = -INFINITY;                           \
        }                                                               \
    }                                                                   \
    union { unsigned d[4]; bf16x8 v; } pa[2];                           \
    _Pragma("unroll")                                                   \
    for (int ks = 0; ks < 2; ++ks)                                      \
      _Pragma("unroll")                                                 \
      for (int w = 0; w < 4; ++w) {                                     \
        int nt = ks * 2 + (w >> 1), rp = (w & 1) * 2;                   \
        unsigned ulo = __float_as_uint(exp2f(sacc[nt][rp]));            \
        unsigned uhi = __float_as_uint(exp2f(sacc[nt][rp + 1]));        \
        (LACC) += __uint_as_float(ulo & 0xffff0000u) + __uint_as_float(uhi & 0xffff0000u); \
        pa[ks].d[w] = (ulo >> 16) | (uhi & 0xffff0000u);                \
      }                                                                 \
    __builtin_amdgcn_s_setprio(1);                                      \
    _Pragma("unroll")                                                   \
    for (int ot = 0; ot < 8; ++ot) {                                    \
      int d = ot * 16 + l15;                                            \
      _Pragma("unroll")                                                 \
      for (int ks = 0; ks < 2; ++ks) {                                  \
        bf16x8 vf = *(const bf16x8*)&(VL)[d * 64 + (((ks * 4 + quad) ^ (d & 7)) * 8)]; \
        (OACC)[ot] = __builtin_amdgcn_mfma_f32_16x16x32_bf16(pa[ks].v, vf, (OACC)[ot], 0, 0, 0); \
      }                                                                 \
    }                                                                   \
    __builtin_amdgcn_s_setprio(0);                                      \
  } while (0)

  bf16x8 qfH[4], qfL[4];
#pragma unroll
  for (int ks = 0; ks < 4; ++ks) {
    qfH[ks] = *(const bf16x8*)(Qh + (size_t)(qbH + l15) * DH + ks * 32 + quad * 8);
    qfL[ks] = *(const bf16x8*)(Qh + (size_t)(qbL + l15) * DH + ks * 32 + quad * 8);
  }

  f32x4 oaccH[8], oaccL[8];
#pragma unroll
  for (int i = 0; i < 8; ++i) { oaccH[i] = zero; oaccL[i] = zero; }
  float lH = 0.f, lL = 0.f;

  // prologue: step-0 tile (always phase 1 -> single tile 0, sub 0)
  STAGE1(0, 0, 0);
  asm volatile("s_waitcnt vmcnt(0)" ::: "memory");
  __builtin_amdgcn_s_barrier();

  for (int t = 0; t < 17; ++t) {
    const int sl = t & 1;
    if (t < 16) STAGESTEP(t + 1, sl ^ 1);   // issue-early into other slot

    if (t <= pr) {                          // phase 1: shared tile t (sub 0)
      const u16* Kl = &Klds[sl][0][0];
      const u16* Vl = &Vlds[sl][0][0];
      if (gp == 0) TILE_BODY(qfH, oaccH, lH, qtHI, t, Kl, Vl);
      else         TILE_BODY(qfL, oaccL, lL, qtLO, t, Kl, Vl);
    } else {                                // phase 2: both groups on HI
      const int uu = t - pr - 1;
      if (gp == 0) {
        const int j = pr + 1 + 2 * uu;
        const u16* Kl = &Klds[sl][0][0];
        const u16* Vl = &Vlds[sl][0][0];
        TILE_BODY(qfH, oaccH, lH, qtHI, j, Kl, Vl);
      } else {
        const int j = pr + 2 + 2 * uu;
        if (j <= qtHI) {
          const u16* Kl = &Klds[sl][1][0];
          const u16* Vl = &Vlds[sl][1][0];
          TILE_BODY(qfH, oaccH, lH, qtHI, j, Kl, Vl);
        }
      }
    }

    if (t < 16) {                           // next step's tiles landed
      asm volatile("s_waitcnt vmcnt(0)" ::: "memory");
      __builtin_amdgcn_s_barrier();
    }
  }

  // reduce l across quads (each lane then holds full l for q-col = l15)
  lH += __shfl_xor(lH, 16); lH += __shfl_xor(lH, 32);
  lL += __shfl_xor(lL, 16); lL += __shfl_xor(lL, 32);

  __syncthreads();                          // all K/V reads done; reuse LDS
  float* Ox = (float*)&Klds[0][0][0];       // 32 KB exchange: [w4][16][128]
  if (gp == 1) {
    float* Ow = Ox + (size_t)w4 * 2048;
#pragma unroll
    for (int ot = 0; ot < 8; ++ot)
#pragma unroll
      for (int r = 0; r < 4; ++r)
        Ow[(quad * 4 + r) * 128 + ot * 16 + l15] = oaccH[ot][r];
    if (quad == 0) Lx[w4 * 16 + l15] = lH;
  }
  __syncthreads();
  if (gp == 0) {                            // HI output: g0 + g1 partials
    const float* Or = Ox + (size_t)w4 * 2048;
    float rl[4];
#pragma unroll
    for (int r = 0; r < 4; ++r) {
      int i = quad * 4 + r;
      rl[r] = 1.0f / (__shfl(lH, i) + Lx[w4 * 16 + i]);
    }
#pragma unroll
    for (int ot = 0; ot < 8; ++ot)
#pragma unroll
      for (int r = 0; r < 4; ++r)
        Og[(size_t)(qbH + quad * 4 + r) * (NH * DH) + h * DH + ot * 16 + l15] =
            f2bf((oaccH[ot][r] + Or[(quad * 4 + r) * 128 + ot * 16 + l15]) * rl[r]);
  } else {                                  // LO output: g1 alone
    float rl[4];
#pragma unroll
    for (int r = 0; r < 4; ++r)
      rl[r] = 1.0f / __shfl(lL, quad * 4 + r);
#pragma unroll
    for (int ot = 0; ot < 8; ++ot)
#pragma unroll
      for (int r = 0; r < 4; ++r)
        Og[(size_t)(qbL + quad * 4 + r) * (NH * DH) + h * DH + ot * 16 + l15] =
            f2bf(oaccL[ot][r] * rl[r]);
  }
#undef TILE_BODY
#undef STAGESTEP
#undef STAGE1
}

// ------------------------------------------------------------------ launch
extern "C" void kernel_launch(void* const* d_in, const int* in_sizes, int n_in,
                              void* d_out, int out_size, void* d_ws, size_t ws_size,
                              hipStream_t stream) {
  (void)in_sizes; (void)n_in; (void)out_size; (void)ws_size;
  const int* positions = (const int*)d_in[0];
  const float* hidden  = (const float*)d_in[1];
  const float* w_qkv   = (const float*)d_in[2];
  const float* w_o     = (const float*)d_in[3];
  const float* q_norm  = (const float*)d_in[4];
  const float* k_norm  = (const float*)d_in[5];
  float* out = (float*)d_out;

  char* ws = (char*)d_ws;                             // peak use 64 MiB
  u16*   Xb    = (u16*)(ws);                          //  8 MiB [dead after GEMM1]
  u16*   WqkvT = (u16*)(ws + ( 8ull << 20));          // 16 MiB [dead after GEMM1]
  u16*   WoT   = (u16*)(ws + (24ull << 20));          //  8 MiB [live till GEMM2]
  u16*   P0    = (u16*)(ws + (32ull << 20));          // 16 MiB: GEMM1 bf16 out (no split)
  // after GEMM1, WqkvT region dead -> Q/K/V live there:
  u16*   Qg    = (u16*)(ws + ( 8ull << 20));          //  8 MiB bf16 [NH][T][D]
  u16*   Kg    = (u16*)(ws + (16ull << 20));          //  4 MiB bf16 [NKV][T][D]
  u16*   Vt    = (u16*)(ws + (20ull << 20));          //  4 MiB bf16 [NKV][D][T] (k-permuted)
  u16*   AttnO = (u16*)(ws + (48ull << 20));          //  8 MiB bf16 [T][NH*D]
  // after rope_vt, P0 region reused:
  u16*   G2P   = (u16*)(ws + (32ull << 20));          // 16 MiB: GEMM2 bf16 partials (2 x 8 MiB)

  prepass<<<dim3(7168), 256, 0, stream>>>(hidden, w_qkv, w_o, Xb, WqkvT, WoT);

  // QKV proj: 128x256 tiles, NO split-K -> 16x16 = 256 blocks (1/CU)
  gemm128x256<<<dim3(256), 512, 0, stream>>>(
      Xb, WqkvT, P0, T_TOK, 4096, HIDDEN, HIDDEN, HIDDEN, 1);

  rope_vt<<<dim3(12288 + 512), 256, 0, stream>>>(P0, positions,
                                                 q_norm, k_norm, Qg, Kg, Vt);

  // balanced paired direct-output attention: 256 blocks = (h, pair)
  attn_kernel<<<dim3(256), 512, 0, stream>>>(Qg, Kg, Vt, AttnO);

  // O-proj: 128x256 tiles, split-K=2 -> 16x8x2 = 256 blocks (1/CU)
  gemm128x256<<<dim3(256), 512, 0, stream>>>(
      AttnO, WoT, G2P, T_TOK, HIDDEN, 1024, NH * DH, NH * DH, 1);
  const int n4 = T_TOK * HIDDEN / 4;
  add_parts2<<<dim3(n4 / 256), 256, 0, stream>>>(
      G2P, G2P + (size_t)T_TOK * HIDDEN, out, n4);
}

// Round 11
// 224.601 us; speedup vs baseline: 1.0578x; 1.0285x over previous
//
#include <hip/hip_runtime.h>
#include <math.h>

#define T_TOK 2048
#define HIDDEN 2048
#define NH 16
#define NKV 8
#define DH 128

typedef unsigned short u16;
typedef __attribute__((ext_vector_type(8))) short bf16x8;
typedef __attribute__((ext_vector_type(4))) float f32x4;

__device__ __forceinline__ u16 f2bf(float f) {
  union { float f; unsigned u; } x; x.f = f;
  unsigned r = (x.u + 0x7fffu + ((x.u >> 16) & 1u)) >> 16;
  return (u16)r;
}

__device__ __forceinline__ float bf2f(u16 v) {
  union { unsigned u; float f; } x; x.u = ((unsigned)v) << 16;
  return x.f;
}

// raw v_exp_f32: 1 TRANS instruction (libm exp2f expands to ~12 range-checked
// instructions without fast-math). exp2(-inf)=0 per ISA -> causal mask OK.
__device__ __forceinline__ float exp2i(float x) {
  float r;
  asm("v_exp_f32 %0, %1" : "=v"(r) : "v"(x));
  return r;
}

__device__ __forceinline__ void gload16(const void* g, void* l) {
  __builtin_amdgcn_global_load_lds((const __attribute__((address_space(1))) void*)g,
                                   (__attribute__((address_space(3))) void*)l,
                                   16, 0, 0);
}

// -------------------------------------------------------------- fused prepass
// b < 4096            : hidden fp32 -> bf16 (Xb)
// 4096 <= b < 6144    : transpose w_qkv [2048][4096] -> WqkvT bf16 [4096][2048]
// 6144 <= b < 7168    : transpose w_o  [2048][2048] -> WoT  bf16 [2048][2048]
__global__ __launch_bounds__(256) void prepass(const float* __restrict__ hidden,
                                               const float* __restrict__ w_qkv,
                                               const float* __restrict__ w_o,
                                               u16* __restrict__ Xb,
                                               u16* __restrict__ WqkvT,
                                               u16* __restrict__ WoT) {
  __shared__ float tile[64][65];
  const int b = blockIdx.x;
  if (b < 4096) {
    int i = b * 256 + threadIdx.x;
    float4 v = ((const float4*)hidden)[i];
    ushort4 o;
    o.x = f2bf(v.x); o.y = f2bf(v.y); o.z = f2bf(v.z); o.w = f2bf(v.w);
    ((ushort4*)Xb)[i] = o;
    return;
  }
  const float* in; u16* out; int R, Cdim, c0, r0;
  if (b < 6144) {
    int bb = b - 4096;
    in = w_qkv; out = WqkvT; R = 2048; Cdim = 4096;
    c0 = (bb & 63) * 64; r0 = (bb >> 6) * 64;
  } else {
    int bb = b - 6144;
    in = w_o; out = WoT; R = 2048; Cdim = 2048;
    c0 = (bb & 31) * 64; r0 = (bb >> 5) * 64;
  }
  const int tx = threadIdx.x & 63, ty = threadIdx.x >> 6;
#pragma unroll
  for (int i = 0; i < 64; i += 4)
    tile[ty + i][tx] = in[(size_t)(r0 + ty + i) * Cdim + c0 + tx];
  __syncthreads();
#pragma unroll
  for (int i = 0; i < 64; i += 4)
    out[(size_t)(c0 + ty + i) * R + r0 + tx] = f2bf(tile[tx][ty + i]);
}

// sum 2 bf16 partial buffers -> fp32 out
__global__ __launch_bounds__(256) void add_parts2(const u16* __restrict__ a,
                                                  const u16* __restrict__ b,
                                                  float* __restrict__ o, int n4) {
  int i = blockIdx.x * blockDim.x + threadIdx.x;
  if (i < n4) {
    ushort4 x = ((const ushort4*)a)[i], y = ((const ushort4*)b)[i];
    float4 z;
    z.x = bf2f(x.x) + bf2f(y.x);
    z.y = bf2f(x.y) + bf2f(y.y);
    z.z = bf2f(x.z) + bf2f(y.z);
    z.w = bf2f(x.w) + bf2f(y.w);
    ((float4*)o)[i] = z;
  }
}

// ------------------------------------- fused RMSNorm+RoPE and V-transpose
// V is written k-PERMUTED within each 64-token tile (sigma-inv) so the attn
// PV B-fragment (pi contraction order) is one contiguous b128 LDS read.
__global__ __launch_bounds__(256) void rope_vt(const u16* __restrict__ qkv,
                                               const int* __restrict__ pos,
                                               const float* __restrict__ qw,
                                               const float* __restrict__ kw,
                                               u16* __restrict__ Qg,
                                               u16* __restrict__ Kg,
                                               u16* __restrict__ Vt) {
  __shared__ float tile[64][65];
  const int b = blockIdx.x;
  if (b < 12288) {
    const int wave = threadIdx.x >> 6, j = threadIdx.x & 63;
    const int idx = b * 4 + wave;
    const int t = idx & 2047, slot = idx >> 11;
    const float QSC = 0.088388347648318447f * 1.4426950408889634f; // scale*log2e
    const size_t base_i = (size_t)t * 4096 + slot * 128;
    float x1 = bf2f(qkv[base_i + j]);
    float x2 = bf2f(qkv[base_i + j + 64]);
    float ss = x1 * x1 + x2 * x2;
#pragma unroll
    for (int m = 1; m < 64; m <<= 1) ss += __shfl_xor(ss, m);
    float r = rsqrtf(ss * (1.0f / 128.0f) + 1e-6f);
    const bool isq = slot < NH;
    const float* w = isq ? qw : kw;
    float xn1 = x1 * r * w[j], xn2 = x2 * r * w[j + 64];
    float fp = (float)pos[t];
    float inv_freq = exp2f(-(float)j * (13.287712379549449f / 64.0f)); // 10000^(-j/64)
    float ang = fp * inv_freq;
    float sn, cs;
    sincosf(ang, &sn, &cs);
    float o1 = xn1 * cs - xn2 * sn;
    float o2 = xn2 * cs + xn1 * sn;
    if (isq) {
      size_t base = ((size_t)slot * T_TOK + t) * DH;
      Qg[base + j] = f2bf(o1 * QSC); Qg[base + 64 + j] = f2bf(o2 * QSC);
    } else {
      size_t base = ((size_t)(slot - NH) * T_TOK + t) * DH;
      Kg[base + j] = f2bf(o1); Kg[base + 64 + j] = f2bf(o2);
    }
    return;
  }
  const int bb = b - 12288;
  const int h = bb & 7, rest = bb >> 3;
  const int t0 = (rest & 31) * 64, d0 = (rest >> 5) * 64;
  const int tx = threadIdx.x & 63, ty = threadIdx.x >> 6;
#pragma unroll
  for (int i = 0; i < 64; i += 4) {
    size_t gi = (size_t)(t0 + ty + i) * 4096 + (NH + NKV) * DH + h * DH + d0 + tx;
    tile[ty + i][tx] = bf2f(qkv[gi]);
  }
  __syncthreads();
  // sigma-inv: output position tx holds original k-index sx within the tile
  const int sx = ((tx >> 5) * 2 + ((tx >> 2) & 1)) * 16 + ((tx >> 3) & 3) * 4 + (tx & 3);
#pragma unroll
  for (int i = 0; i < 64; i += 4)
    Vt[((size_t)h * DH + d0 + ty + i) * T_TOK + t0 + tx] = f2bf(tile[sx][ty + i]);
}

// ------------------------------------------------------------- GEMM 128x256
// (unchanged — verified counted-vmcnt pipeline)
__global__ __launch_bounds__(512, 2) void gemm128x256(const u16* __restrict__ A,
                                                      const u16* __restrict__ Bt,
                                                      void* __restrict__ Cout,
                                                      int M, int N, int K,
                                                      int lda, int ldb, int obf16) {
  __shared__ __attribute__((aligned(128))) char lds[98304];

  const int nx = N >> 8, ny = M >> 7;
  const int flat = blockIdx.x;
  const int per = gridDim.x >> 3;
  const int swz = (flat & 7) * per + (flat >> 3);
  const int by = swz % ny;
  const int rest = swz / ny;
  const int bx = rest % nx;
  const int bz = rest / nx;
  const int m0 = by << 7, n0 = bx << 8;
  A += (size_t)bz * K;
  Bt += (size_t)bz * K;

  const int tid = threadIdx.x;
  const int wave = tid >> 6, lane = tid & 63;
  const int l15 = lane & 15, quad = lane >> 4;
  const int wr = wave >> 2, wc = wave & 3;

  size_t aoff;
  {
    int chunk = tid;
    int line = chunk >> 3;
    int ls8 = (chunk & 7) ^ (line & 7);
    int row = line * 2 + (ls8 >> 2);
    int ks = ls8 & 3;
    aoff = (size_t)(m0 + row) * lda + ks * 8;
  }
  size_t boff[2];
#pragma unroll
  for (int c = 0; c < 2; ++c) {
    int chunk = c * 512 + tid;
    int line = chunk >> 3;
    int ls8 = (chunk & 7) ^ (line & 7);
    int row = line * 2 + (ls8 >> 2);
    int ks = ls8 & 3;
    boff[c] = (size_t)(n0 + row) * ldb + ks * 8;
  }

#define STAGE(tt) do {                                                   \
    char* da = lds + ((tt) & 3) * 8192 + wave * 1024;                    \
    char* db = lds + 32768 + ((tt) & 3) * 16384 + wave * 1024;           \
    const int kk = (tt) * 32;                                            \
    gload16(A + aoff + kk, da);                                          \
    gload16(Bt + boff[0] + kk, db);                                      \
    gload16(Bt + boff[1] + kk, db + 8192);                               \
  } while (0)

  const int fragoff = (l15 >> 1) * 128 +
                      (((((l15 & 1) << 2) | quad) ^ ((l15 >> 1) & 7)) << 4);

  const f32x4 zero = {0.f, 0.f, 0.f, 0.f};
  f32x4 acc[4][4];
#pragma unroll
  for (int i = 0; i < 4; ++i)
#pragma unroll
    for (int j = 0; j < 4; ++j) acc[i][j] = zero;

  const int NT = K >> 5;
  STAGE(0); STAGE(1); STAGE(2);
  asm volatile("s_waitcnt vmcnt(6)" ::: "memory");
  __builtin_amdgcn_s_barrier();

  for (int t = 0; t < NT; ++t) {
    const char* As = lds + (t & 3) * 8192 + wr * 4096 + fragoff;
    const char* Bs = lds + 32768 + (t & 3) * 16384 + wc * 4096 + fragoff;
    bf16x8 af[4], bfr[4];
#pragma unroll
    for (int mt = 0; mt < 4; ++mt) af[mt] = *(const bf16x8*)(As + mt * 1024);
#pragma unroll
    for (int nt = 0; nt < 4; ++nt) bfr[nt] = *(const bf16x8*)(Bs + nt * 1024);

    if (t + 3 < NT) STAGE(t + 3);

    __builtin_amdgcn_s_setprio(1);
#pragma unroll
    for (int mt = 0; mt < 4; ++mt)
#pragma unroll
      for (int nt = 0; nt < 4; ++nt)
        acc[mt][nt] = __builtin_amdgcn_mfma_f32_16x16x32_bf16(af[mt], bfr[nt], acc[mt][nt], 0, 0, 0);
    __builtin_amdgcn_s_setprio(0);

    const int rem = NT - 1 - t;
    if (rem >= 3)      asm volatile("s_waitcnt vmcnt(6)" ::: "memory");
    else if (rem == 2) asm volatile("s_waitcnt vmcnt(3)" ::: "memory");
    else if (rem == 1) asm volatile("s_waitcnt vmcnt(0)" ::: "memory");
    if (rem > 0) __builtin_amdgcn_s_barrier();
  }
#undef STAGE

  if (obf16) {
    u16* C = (u16*)Cout + (size_t)bz * M * N;
#pragma unroll
    for (int mt = 0; mt < 4; ++mt)
#pragma unroll
      for (int nt = 0; nt < 4; ++nt)
#pragma unroll
        for (int r = 0; r < 4; ++r)
          C[(size_t)(m0 + wr * 64 + mt * 16 + quad * 4 + r) * N + n0 + wc * 64 + nt * 16 + l15] =
              f2bf(acc[mt][nt][r]);
  } else {
    float* C = (float*)Cout + (size_t)bz * M * N;
#pragma unroll
    for (int mt = 0; mt < 4; ++mt)
#pragma unroll
      for (int nt = 0; nt < 4; ++nt)
#pragma unroll
        for (int r = 0; r < 4; ++r)
          C[(size_t)(m0 + wr * 64 + mt * 16 + quad * 4 + r) * N + n0 + wc * 64 + nt * 16 + l15] =
              acc[mt][nt][r];
  }
}

// ------------------------------------------------------------- flash attn
// Balanced cooperative pairing (R10 structure, verified) with raw v_exp_f32
// softmax. Block b=(h,pr): q-tiles HI=31-pr, LO=pr. group0 = waves 0-3,
// group1 = 4-7 (SIMD s hosts one wave of each group). 17 uniform steps:
//  phase 1 (t<=pr): ONE staged tile t; g0 computes HI, g1 computes LO.
//  phase 2 (t>pr):  TWO staged tiles pr+1+2u (g0,HI) and pr+2+2u (g1,HI).
// Per-wave body: 16-row waves, swapped QK^T, in-reg pi-packed P,
// k-permuted V -> conflict-free b128 vf. Direct bf16 output, no merge.
__global__ __launch_bounds__(512, 2) void attn_kernel(const u16* __restrict__ Qg,
                                                      const u16* __restrict__ Kg,
                                                      const u16* __restrict__ Vtg,
                                                      u16* __restrict__ Og) {
  __shared__ u16 Klds[2][2][64 * 128];   // [slot][sub][s][d], group g at g^(s&15)
  __shared__ u16 Vlds[2][2][128 * 64];   // [slot][sub][d][p], group g at g^(d&7)
  __shared__ float Lx[64];               // l exchange for HI: [w4][16]
  const int tid = threadIdx.x;
  const int wave = tid >> 6, lane = tid & 63;
  const int l15 = lane & 15, quad = lane >> 4;
  const int gp = wave >> 2, w4 = wave & 3;
  const int b = blockIdx.x;
  const int h = b & 15, pr = b >> 4;
  const int kvh = h >> 1;
  const int qtHI = 31 - pr, qtLO = pr;
  const f32x4 zero = {0.f, 0.f, 0.f, 0.f};

  const u16* Qh = Qg + (size_t)h * T_TOK * DH;
  const u16* Kh = Kg + (size_t)kvh * T_TOK * DH;
  const u16* Vh = Vtg + (size_t)kvh * DH * T_TOK;
  const int qbH = qtHI * 64 + w4 * 16;   // HI rows (both groups, phase 2)
  const int qbL = qtLO * 64 + w4 * 16;   // LO rows (group 1, phase 1)

#define STAGE1(jj, sl, ss) do {                                         \
    u16* Kd = &Klds[sl][ss][0]; u16* Vd = &Vlds[sl][ss][0];             \
    _Pragma("unroll")                                                   \
    for (int c = 0; c < 2; ++c) {                                       \
      int chunk = wave * 2 + c;                                         \
      int sL = chunk * 64 + lane;                                       \
      { int ssk = sL >> 4;                                              \
        int g = (sL & 15) ^ (ssk & 15);                                 \
        gload16(Kh + ((size_t)((jj) * 64 + ssk)) * DH + g * 8, Kd + chunk * 512); } \
      { int d = sL >> 3;                                                \
        int gv = (sL & 7) ^ (d & 7);                                    \
        gload16(Vh + (size_t)d * T_TOK + (jj) * 64 + gv * 8, Vd + chunk * 512); } \
    } } while (0)

#define STAGESTEP(ts, sl) do {                                          \
    if ((ts) <= pr) { STAGE1((ts), (sl), 0); }                          \
    else {                                                              \
      int uu = (ts) - pr - 1;                                           \
      int jA = pr + 1 + 2 * uu;                                         \
      STAGE1(jA, (sl), 0);                                              \
      if (jA + 1 <= qtHI) STAGE1(jA + 1, (sl), 1);                      \
    } } while (0)

// verified per-tile body; softmax uses raw v_exp_f32 (exp2i)
#define TILE_BODY(QF, OACC, LACC, QT, JJ, KL, VL) do {                  \
    f32x4 sacc[4];                                                      \
    _Pragma("unroll")                                                   \
    for (int nt = 0; nt < 4; ++nt) sacc[nt] = zero;                     \
    __builtin_amdgcn_s_setprio(1);                                      \
    _Pragma("unroll")                                                   \
    for (int nt = 0; nt < 4; ++nt) {                                    \
      int sr = nt * 16 + l15;                                           \
      _Pragma("unroll")                                                 \
      for (int ks = 0; ks < 4; ++ks) {                                  \
        bf16x8 kf = *(const bf16x8*)&(KL)[sr * 128 + (((ks * 4 + quad) ^ (sr & 15)) * 8)]; \
        sacc[nt] = __builtin_amdgcn_mfma_f32_16x16x32_bf16(kf, (QF)[ks], sacc[nt], 0, 0, 0); \
      }                                                                 \
    }                                                                   \
    __builtin_amdgcn_s_setprio(0);                                      \
    if ((JJ) == (QT)) {                                                 \
      int q = (QT) * 64 + w4 * 16 + l15;                                \
      _Pragma("unroll")                                                 \
      for (int nt = 0; nt < 4; ++nt)                                    \
        _Pragma("unroll")                                               \
        for (int r = 0; r < 4; ++r) {                                   \
          int k = (JJ) * 64 + nt * 16 + quad * 4 + r;                   \
          if (k > q) sacc[nt][r] = -INFINITY;                           \
        }                                                               \
    }                                                                   \
    union { unsigned d[4]; bf16x8 v; } pa[2];                           \
    _Pragma("unroll")                                                   \
    for (int ks = 0; ks < 2; ++ks)                                      \
      _Pragma("unroll")                                                 \
      for (int w = 0; w < 4; ++w) {                                     \
        int nt = ks * 2 + (w >> 1), rp = (w & 1) * 2;                   \
        unsigned ulo = __float_as_uint(exp2i(sacc[nt][rp]));            \
        unsigned uhi = __float_as_uint(exp2i(sacc[nt][rp + 1]));        \
        (LACC) += __uint_as_float(ulo & 0xffff0000u) + __uint_as_float(uhi & 0xffff0000u); \
        pa[ks].d[w] = (ulo >> 16) | (uhi & 0xffff0000u);                \
      }                                                                 \
    __builtin_amdgcn_s_setprio(1);                                      \
    _Pragma("unroll")                                                   \
    for (int ot = 0; ot < 8; ++ot) {                                    \
      int d = ot * 16 + l15;                                            \
      _Pragma("unroll")                                                 \
      for (int ks = 0; ks < 2; ++ks) {                                  \
        bf16x8 vf = *(const bf16x8*)&(VL)[d * 64 + (((ks * 4 + quad) ^ (d & 7)) * 8)]; \
        (OACC)[ot] = __builtin_amdgcn_mfma_f32_16x16x32_bf16(pa[ks].v, vf, (OACC)[ot], 0, 0, 0); \
      }                                                                 \
    }                                                                   \
    __builtin_amdgcn_s_setprio(0);                                      \
  } while (0)

  bf16x8 qfH[4], qfL[4];
#pragma unroll
  for (int ks = 0; ks < 4; ++ks) {
    qfH[ks] = *(const bf16x8*)(Qh + (size_t)(qbH + l15) * DH + ks * 32 + quad * 8);
    qfL[ks] = *(const bf16x8*)(Qh + (size_t)(qbL + l15) * DH + ks * 32 + quad * 8);
  }

  f32x4 oaccH[8], oaccL[8];
#pragma unroll
  for (int i = 0; i < 8; ++i) { oaccH[i] = zero; oaccL[i] = zero; }
  float lH = 0.f, lL = 0.f;

  // prologue: step-0 tile (always phase 1 -> single tile 0, sub 0)
  STAGE1(0, 0, 0);
  asm volatile("s_waitcnt vmcnt(0)" ::: "memory");
  __builtin_amdgcn_s_barrier();

  for (int t = 0; t < 17; ++t) {
    const int sl = t & 1;
    if (t < 16) STAGESTEP(t + 1, sl ^ 1);   // issue-early into other slot

    if (t <= pr) {                          // phase 1: shared tile t (sub 0)
      const u16* Kl = &Klds[sl][0][0];
      const u16* Vl = &Vlds[sl][0][0];
      if (gp == 0) TILE_BODY(qfH, oaccH, lH, qtHI, t, Kl, Vl);
      else         TILE_BODY(qfL, oaccL, lL, qtLO, t, Kl, Vl);
    } else {                                // phase 2: both groups on HI
      const int uu = t - pr - 1;
      if (gp == 0) {
        const int j = pr + 1 + 2 * uu;
        const u16* Kl = &Klds[sl][0][0];
        const u16* Vl = &Vlds[sl][0][0];
        TILE_BODY(qfH, oaccH, lH, qtHI, j, Kl, Vl);
      } else {
        const int j = pr + 2 + 2 * uu;
        if (j <= qtHI) {
          const u16* Kl = &Klds[sl][1][0];
          const u16* Vl = &Vlds[sl][1][0];
          TILE_BODY(qfH, oaccH, lH, qtHI, j, Kl, Vl);
        }
      }
    }

    if (t < 16) {                           // next step's tiles landed
      asm volatile("s_waitcnt vmcnt(0)" ::: "memory");
      __builtin_amdgcn_s_barrier();
    }
  }

  // reduce l across quads (each lane then holds full l for q-col = l15)
  lH += __shfl_xor(lH, 16); lH += __shfl_xor(lH, 32);
  lL += __shfl_xor(lL, 16); lL += __shfl_xor(lL, 32);

  __syncthreads();                          // all K/V reads done; reuse LDS
  float* Ox = (float*)&Klds[0][0][0];       // 32 KB exchange: [w4][16][128]
  if (gp == 1) {
    float* Ow = Ox + (size_t)w4 * 2048;
#pragma unroll
    for (int ot = 0; ot < 8; ++ot)
#pragma unroll
      for (int r = 0; r < 4; ++r)
        Ow[(quad * 4 + r) * 128 + ot * 16 + l15] = oaccH[ot][r];
    if (quad == 0) Lx[w4 * 16 + l15] = lH;
  }
  __syncthreads();
  if (gp == 0) {                            // HI output: g0 + g1 partials
    const float* Or = Ox + (size_t)w4 * 2048;
    float rl[4];
#pragma unroll
    for (int r = 0; r < 4; ++r) {
      int i = quad * 4 + r;
      rl[r] = 1.0f / (__shfl(lH, i) + Lx[w4 * 16 + i]);
    }
#pragma unroll
    for (int ot = 0; ot < 8; ++ot)
#pragma unroll
      for (int r = 0; r < 4; ++r)
        Og[(size_t)(qbH + quad * 4 + r) * (NH * DH) + h * DH + ot * 16 + l15] =
            f2bf((oaccH[ot][r] + Or[(quad * 4 + r) * 128 + ot * 16 + l15]) * rl[r]);
  } else {                                  // LO output: g1 alone
    float rl[4];
#pragma unroll
    for (int r = 0; r < 4; ++r)
      rl[r] = 1.0f / __shfl(lL, quad * 4 + r);
#pragma unroll
    for (int ot = 0; ot < 8; ++ot)
#pragma unroll
      for (int r = 0; r < 4; ++r)
        Og[(size_t)(qbL + quad * 4 + r) * (NH * DH) + h * DH + ot * 16 + l15] =
            f2bf(oaccL[ot][r] * rl[r]);
  }
#undef TILE_BODY
#undef STAGESTEP
#undef STAGE1
}

// ------------------------------------------------------------------ launch
extern "C" void kernel_launch(void* const* d_in, const int* in_sizes, int n_in,
                              void* d_out, int out_size, void* d_ws, size_t ws_size,
                              hipStream_t stream) {
  (void)in_sizes; (void)n_in; (void)out_size; (void)ws_size;
  const int* positions = (const int*)d_in[0];
  const float* hidden  = (const float*)d_in[1];
  const float* w_qkv   = (const float*)d_in[2];
  const float* w_o     = (const float*)d_in[3];
  const float* q_norm  = (const float*)d_in[4];
  const float* k_norm  = (const float*)d_in[5];
  float* out = (float*)d_out;

  char* ws = (char*)d_ws;                             // peak use 64 MiB
  u16*   Xb    = (u16*)(ws);                          //  8 MiB [dead after GEMM1]
  u16*   WqkvT = (u16*)(ws + ( 8ull << 20));          // 16 MiB [dead after GEMM1]
  u16*   WoT   = (u16*)(ws + (24ull << 20));          //  8 MiB [live till GEMM2]
  u16*   P0    = (u16*)(ws + (32ull << 20));          // 16 MiB: GEMM1 bf16 out (no split)
  // after GEMM1, WqkvT region dead -> Q/K/V live there:
  u16*   Qg    = (u16*)(ws + ( 8ull << 20));          //  8 MiB bf16 [NH][T][D]
  u16*   Kg    = (u16*)(ws + (16ull << 20));          //  4 MiB bf16 [NKV][T][D]
  u16*   Vt    = (u16*)(ws + (20ull << 20));          //  4 MiB bf16 [NKV][D][T] (k-permuted)
  u16*   AttnO = (u16*)(ws + (48ull << 20));          //  8 MiB bf16 [T][NH*D]
  // after rope_vt, P0 region reused:
  u16*   G2P   = (u16*)(ws + (32ull << 20));          // 16 MiB: GEMM2 bf16 partials (2 x 8 MiB)

  prepass<<<dim3(7168), 256, 0, stream>>>(hidden, w_qkv, w_o, Xb, WqkvT, WoT);

  // QKV proj: 128x256 tiles, NO split-K -> 16x16 = 256 blocks (1/CU)
  gemm128x256<<<dim3(256), 512, 0, stream>>>(
      Xb, WqkvT, P0, T_TOK, 4096, HIDDEN, HIDDEN, HIDDEN, 1);

  rope_vt<<<dim3(12288 + 512), 256, 0, stream>>>(P0, positions,
                                                 q_norm, k_norm, Qg, Kg, Vt);

  // balanced paired direct-output attention: 256 blocks = (h, pair)
  attn_kernel<<<dim3(256), 512, 0, stream>>>(Qg, Kg, Vt, AttnO);

  // O-proj: 128x256 tiles, split-K=2 -> 16x8x2 = 256 blocks (1/CU)
  gemm128x256<<<dim3(256), 512, 0, stream>>>(
      AttnO, WoT, G2P, T_TOK, HIDDEN, 1024, NH * DH, NH * DH, 1);
  const int n4 = T_TOK * HIDDEN / 4;
  add_parts2<<<dim3(n4 / 256), 256, 0, stream>>>(
      G2P, G2P + (size_t)T_TOK * HIDDEN, out, n4);
}